// Round 6
// baseline (200.407 us; speedup 1.0000x reference)
//
#include <hip/hip_runtime.h>

// FullGRUODECell_Autonomous_fine — MI355X (gfx950)
//
// dh = (1-z)*(u-h);  z = sigmoid(h@Whz^T + hz);  u = tanh((r*h)@Whh^T);
// r = sigmoid(h@Whr^T);  hz[b,i] = sum_{j,k} h[b,j] h[b,k] Wfine[i*256+j,k]
//
// hz = G @ Wf^T with G[b, j*256+k]=h[b,j]h[b,k], Wf = Wfine viewed [256][65536].
// K1 k_pre:  h f32 -> hh fp16.
// K2 k_gemm: MFMA fp16, 256x256 tile, 64 K-chunks x 4 m-tiles (XCD-colocated).
//    Per step: A 16KB (hh fp16) + B 32KB (Wf f32, converted in-reg) staged via
//    global_load_lds with XOR-swizzled per-lane SOURCE addresses (linear LDS
//    dest, same XOR on ds_read => conflict-free reads). Depth-3 pipeline,
//    counted vmcnt(6) + raw s_barrier, setprio around MFMA cluster.
// K3 k_final: gates (VALU) + unrolled hz partial reduction + epilogue.

typedef _Float16 f16;
typedef _Float16 f16x8 __attribute__((ext_vector_type(8)));
typedef _Float16 f16x4 __attribute__((ext_vector_type(4)));
typedef float f32x4 __attribute__((ext_vector_type(4)));

__device__ __forceinline__ void gld_lds16(const void* gp, void* lp) {
  __builtin_amdgcn_global_load_lds(
      (const __attribute__((address_space(1))) unsigned int*)gp,
      (__attribute__((address_space(3))) unsigned int*)lp, 16, 0, 0);
}

// ---------------- K1: h f32 -> fp16
__global__ __launch_bounds__(256) void k_pre(
    const float* __restrict__ h, f16* __restrict__ hh) {
  const int base = (blockIdx.x * 256 + threadIdx.x) * 16;  // 64 wgs cover 262144
  #pragma unroll
  for (int i = 0; i < 2; ++i) {
    float4 a = *(const float4*)(h + base + i * 8);
    float4 b = *(const float4*)(h + base + i * 8 + 4);
    f16x8 o;
    o[0] = (f16)a.x; o[1] = (f16)a.y; o[2] = (f16)a.z; o[3] = (f16)a.w;
    o[4] = (f16)b.x; o[5] = (f16)b.y; o[6] = (f16)b.z; o[7] = (f16)b.w;
    *(f16x8*)(hh + base + i * 8) = o;
  }
}

// ---------------- K2: fused-convert MFMA GEMM, depth-3 counted-vmcnt pipeline
__global__ __launch_bounds__(512, 1) void k_gemm(
    const f16* __restrict__ hh, const float* __restrict__ Wf,
    f16* __restrict__ part) {
  __shared__ __align__(16) f16   Abuf[3][8192];  // 3 x 16KB: [row 0..255][4 slots x 8 halfs]
  __shared__ __align__(16) float Bbuf[3][8192];  // 3 x 32KB: [col 0..255][8 slots x 4 floats]
  __shared__ __align__(8)  f16   hj_lds[1024];   // [row][4 j]
  const int bid = blockIdx.x;
  // XCD colocate: kc's 4 m-tiles land on one XCD
  const int kc = (bid & 7) + ((bid >> 5) << 3);
  const int mt = (bid >> 3) & 3;
  const int tid = threadIdx.x;
  const int wid = tid >> 6;
  const int l = tid & 63;
  const int lg = l >> 4, lr = l & 15;
  const int wm = wid >> 2, wn = wid & 3;

  if (tid < 256) {  // h[row][j] for this kc's 4 j-values
    f16x4 hv = *(const f16x4*)(hh + (mt * 256 + tid) * 256 + kc * 4);
    *(f16x4*)(hj_lds + tid * 4) = hv;
  }

  // A staging: 2 instrs/wave, chunk i rows (wid*2+i)*16 + (l>>2), slot q=l&3.
  // Source pre-XOR: hh[mt*256+row][(n&7)*32 + (q ^ ((row>>1)&3))*8]
  // ((row+16)>>1)&3 == (row>>1)&3, so one base serves both chunks.
  const int arow = (wid * 2) * 16 + (l >> 2);
  const int aq = l & 3;
  const f16* abase = hh + (size_t)(mt * 256 + arow) * 256 + ((aq ^ ((arow >> 1) & 3)) * 8);
  // B staging: 4 instrs/wave, rows wid*32 + i*8 + (l>>3), slot s=l&7.
  // Source pre-XOR: Wf[row][kc*1024 + koff + (s ^ (row&7))*4]; (row+8)&7 == row&7.
  const int brow = wid * 32 + (l >> 3);
  const int bs = l & 7;
  const float* bbase = Wf + (size_t)brow * 65536 + (size_t)kc * 1024 + ((bs ^ (brow & 7)) * 4);

  f32x4 acc[8][4];
  #pragma unroll
  for (int mi = 0; mi < 8; ++mi)
    #pragma unroll
    for (int ni = 0; ni < 4; ++ni)
      acc[mi][ni] = f32x4{0.f, 0.f, 0.f, 0.f};

  auto issue = [&](int n, int b3) {
    const int aoff = (n & 7) * 32;
    gld_lds16(abase + aoff,                 &Abuf[b3][((wid * 2 + 0) * 16) * 32]);
    gld_lds16(abase + aoff + 16 * 256,      &Abuf[b3][((wid * 2 + 1) * 16) * 32]);
    const int koff = ((n >> 3) << 8) + ((n & 7) << 5);
    gld_lds16(bbase + koff,                 &Bbuf[b3][(wid * 32 + 0) * 32]);
    gld_lds16(bbase + koff + 8 * 65536,     &Bbuf[b3][(wid * 32 + 8) * 32]);
    gld_lds16(bbase + koff + 16 * 65536,    &Bbuf[b3][(wid * 32 + 16) * 32]);
    gld_lds16(bbase + koff + 24 * 65536,    &Bbuf[b3][(wid * 32 + 24) * 32]);
  };
  issue(0, 0);
  issue(1, 1);
  __syncthreads();  // hj visible; prologue stages drained (one-time cost)

  f16 hjv[8];
  #pragma unroll
  for (int n = 0; n < 32; ++n) {
    // drain stage(n) (issued 2 steps ago); stage(n+1)'s 6 ops stay in flight
    if (n < 31) asm volatile("s_waitcnt vmcnt(6)" ::: "memory");
    else        asm volatile("s_waitcnt vmcnt(0)" ::: "memory");
    __builtin_amdgcn_s_barrier();
    if (n + 2 < 32) issue(n + 2, (n + 2) % 3);  // buf(n+2)%3 = buf(n-1): readers done
    if ((n & 7) == 0) {
      const int jj = n >> 3;
      #pragma unroll
      for (int mi = 0; mi < 8; ++mi)
        hjv[mi] = hj_lds[(wm * 128 + mi * 16 + lr) * 4 + jj];
    }
    const int buf = n % 3;
    f16x8 afr[8], bfr[4];
    #pragma unroll
    for (int mi = 0; mi < 8; ++mi) {
      const int r = wm * 128 + mi * 16 + lr;
      f16x8 av = *(const f16x8*)(&Abuf[buf][r * 32 + (lg ^ ((r >> 1) & 3)) * 8]);
      afr[mi] = av * hjv[mi];  // G[b, j*256+k] = h[b,k]*h[b,j]
    }
    #pragma unroll
    for (int ni = 0; ni < 4; ++ni) {
      const int c = wn * 64 + ni * 16 + lr;
      f32x4 fa = *(const f32x4*)(&Bbuf[buf][c * 32 + ((2 * lg) ^ (c & 7)) * 4]);
      f32x4 fb = *(const f32x4*)(&Bbuf[buf][c * 32 + ((2 * lg + 1) ^ (c & 7)) * 4]);
      f16x8 bv;
      bv[0] = (f16)fa[0]; bv[1] = (f16)fa[1]; bv[2] = (f16)fa[2]; bv[3] = (f16)fa[3];
      bv[4] = (f16)fb[0]; bv[5] = (f16)fb[1]; bv[6] = (f16)fb[2]; bv[7] = (f16)fb[3];
      bfr[ni] = bv;
    }
    __builtin_amdgcn_s_setprio(1);
    #pragma unroll
    for (int mi = 0; mi < 8; ++mi)
      #pragma unroll
      for (int ni = 0; ni < 4; ++ni)
        acc[mi][ni] = __builtin_amdgcn_mfma_f32_16x16x32_f16(
            afr[mi], bfr[ni], acc[mi][ni], 0, 0, 0);
    __builtin_amdgcn_s_setprio(0);
  }

  // fp16 partial tile: part[kc][mt*256 + row][col]
  f16* pout = part + ((size_t)kc << 18) + (mt << 16);
  #pragma unroll
  for (int mi = 0; mi < 8; ++mi) {
    #pragma unroll
    for (int r = 0; r < 4; ++r) {
      const int b = wm * 128 + mi * 16 + lg * 4 + r;  // C row = (l>>4)*4 + reg
      #pragma unroll
      for (int ni = 0; ni < 4; ++ni)
        pout[(b << 8) + wn * 64 + ni * 16 + lr] = (f16)acc[mi][ni][r];  // col = l&15
    }
  }
}

// ---------------- K3: fused gates + hz reduction + epilogue
__global__ __launch_bounds__(256) void k_final(
    const float* __restrict__ h, const float* __restrict__ Whr,
    const float* __restrict__ Whz, const float* __restrict__ Whh,
    const f16* __restrict__ part, float* __restrict__ out) {
  __shared__ float hs[4][256];
  __shared__ float rhs[4][256];
  __shared__ float hzs[4][256];
  const int t = threadIdx.x;
  const int b0 = blockIdx.x << 2;  // 4 batch rows per wg
  {  // stage h
    const int row = t >> 6, col = (t & 63) << 2;
    *(float4*)(&hs[row][col]) = *(const float4*)(h + (b0 + row) * 256 + col);
  }
  {  // hz partial reduction: unrolled, 8 independent in-flight loads
    const int row = t >> 6, c4 = (t & 63) << 2;
    const f16* p = part + (b0 + row) * 256 + c4;
    float s0 = 0.f, s1 = 0.f, s2 = 0.f, s3 = 0.f;
    #pragma unroll
    for (int kb = 0; kb < 8; ++kb) {
      f16x4 v[8];
      #pragma unroll
      for (int u = 0; u < 8; ++u)
        v[u] = *(const f16x4*)(p + ((size_t)(kb * 8 + u) << 18));
      #pragma unroll
      for (int u = 0; u < 8; ++u) {
        s0 += (float)v[u][0]; s1 += (float)v[u][1];
        s2 += (float)v[u][2]; s3 += (float)v[u][3];
      }
    }
    hzs[row][c4] = s0; hzs[row][c4 + 1] = s1;
    hzs[row][c4 + 2] = s2; hzs[row][c4 + 3] = s3;
  }
  __syncthreads();
  float az[4];
  {  // r/z gates: thread t <-> output col t
    float ar[4] = {0.f, 0.f, 0.f, 0.f};
    az[0] = az[1] = az[2] = az[3] = 0.f;
    const float* wr = Whr + t * 256;
    const float* wz = Whz + t * 256;
    for (int k = 0; k < 256; k += 4) {
      float4 a = *(const float4*)(wr + k);
      float4 c = *(const float4*)(wz + k);
      #pragma unroll
      for (int q = 0; q < 4; ++q) {
        const float* hp = &hs[q][k];
        ar[q] = fmaf(a.x, hp[0], fmaf(a.y, hp[1], fmaf(a.z, hp[2], fmaf(a.w, hp[3], ar[q]))));
        az[q] = fmaf(c.x, hp[0], fmaf(c.y, hp[1], fmaf(c.z, hp[2], fmaf(c.w, hp[3], az[q]))));
      }
    }
    #pragma unroll
    for (int q = 0; q < 4; ++q) {
      const float r = 1.f / (1.f + __expf(-ar[q]));
      rhs[q][t] = r * hs[q][t];
    }
  }
  __syncthreads();
  {  // u gate + epilogue
    float au[4] = {0.f, 0.f, 0.f, 0.f};
    const float* wh = Whh + t * 256;
    for (int k = 0; k < 256; k += 4) {
      float4 a = *(const float4*)(wh + k);
      #pragma unroll
      for (int q = 0; q < 4; ++q) {
        const float* hp = &rhs[q][k];
        au[q] = fmaf(a.x, hp[0], fmaf(a.y, hp[1], fmaf(a.z, hp[2], fmaf(a.w, hp[3], au[q]))));
      }
    }
    #pragma unroll
    for (int q = 0; q < 4; ++q) {
      const float z = 1.f / (1.f + __expf(-(az[q] + hzs[q][t])));
      const float u = tanhf(au[q]);
      out[(b0 + q) * 256 + t] = (1.f - z) * (u - hs[q][t]);
    }
  }
}

extern "C" void kernel_launch(void* const* d_in, const int* in_sizes, int n_in,
                              void* d_out, int out_size, void* d_ws, size_t ws_size,
                              hipStream_t stream) {
  const float* h   = (const float*)d_in[1];
  const float* Whr = (const float*)d_in[2];
  const float* Whz = (const float*)d_in[3];
  const float* Whh = (const float*)d_in[4];
  const float* Wf  = (const float*)d_in[5];
  float* out = (float*)d_out;
  char* ws = (char*)d_ws;

  f16* hh   = (f16*)(ws);                // 512 KiB (pad to 1 MiB)
  f16* part = (f16*)(ws + (1u << 20));   // 32 MiB (64 x 1024 x 256)

  k_pre<<<dim3(64), dim3(256), 0, stream>>>(h, hh);
  k_gemm<<<dim3(256), dim3(512), 0, stream>>>(hh, Wf, part);
  k_final<<<dim3(256), dim3(256), 0, stream>>>(h, Whr, Whz, Whh, part, out);
}